// Round 3
// baseline (204.156 us; speedup 1.0000x reference)
//
#include <hip/hip_runtime.h>
#include <math.h>

#define D 256
#define NH 8
#define NL 4
#define NP 4
#define DFF 2048
#define HD 32
#define BB 2
#define LEN 5440
#define MROWS (BB * LEN)   // 10880 = 85*128 = 340*32 = 2720*4

typedef __attribute__((ext_vector_type(8))) short short8;
typedef __attribute__((ext_vector_type(4))) float f32x4;
typedef unsigned int uint32;

__device__ __forceinline__ unsigned short f2bf(float f) {
    uint32 u = __float_as_uint(f);
    u += 0x7FFF + ((u >> 16) & 1);           // round-to-nearest-even
    return (unsigned short)(u >> 16);
}
__device__ __forceinline__ float bf2f(unsigned short h) {
    return __uint_as_float(((uint32)h) << 16);
}
__device__ __forceinline__ uint32 pack2(float a, float b) {
    return (uint32)f2bf(a) | ((uint32)f2bf(b) << 16);
}

// async global->LDS, 16B per lane. LDS dest is wave-uniform base + lane*16.
__device__ __forceinline__ void gl16(const unsigned short* g, unsigned short* l) {
    __builtin_amdgcn_global_load_lds(
        (const __attribute__((address_space(1))) unsigned int*)g,
        (__attribute__((address_space(3))) unsigned int*)l, 16, 0, 0);
}

// XCD-affinity swizzle: 85 row-tiles x ncols col-tiles.
__device__ __forceinline__ void swz85(int b, int ncols, int& row, int& col) {
    const int gsz = ncols << 3;
    const int full = 10 * gsz;
    if (b < full) {
        const int g = b / gsz, idx = b - g * gsz;
        row = (g << 3) + (idx & 7);
        col = idx >> 3;
    } else {
        const int idx = b - full;
        row = 80 + idx % 5;
        col = idx / 5;
    }
}

// ---------------------------------------------------------------------------
// prep_a: wqv transposes (fp32 [KxN] -> bf16 [NxK]) + bias concat. 161 blocks.
// ---------------------------------------------------------------------------
__global__ void prep_a(const float* __restrict__ w_value, const float* __restrict__ w_off,
                       const float* __restrict__ w_attn,
                       const float* __restrict__ b_value, const float* __restrict__ b_off,
                       const float* __restrict__ b_attn,
                       unsigned short* __restrict__ wqvT, float* __restrict__ bqv) {
    __shared__ float tile[32][33];
    const int blk = blockIdx.x;
    const int t = threadIdx.x;
    if (blk >= 160) {
        for (int i = t; i < 640; i += 256)
            bqv[i] = (i < 256) ? b_value[i] : (i < 512 ? b_off[i - 256] : b_attn[i - 512]);
        return;
    }
    const float* W; unsigned short* WT; int N, tid;
    if (blk < 64)       { W = w_value; WT = wqvT;             N = 256; tid = blk; }
    else if (blk < 128) { W = w_off;   WT = wqvT + 256 * 256; N = 256; tid = blk - 64; }
    else                { W = w_attn;  WT = wqvT + 512 * 256; N = 128; tid = blk - 128; }
    const int K = 256;
    const int ntx = N >> 5;
    const int nb = (tid % ntx) * 32, kb = (tid / ntx) * 32;
    const int tx = t & 31, ty = t >> 5;
#pragma unroll
    for (int i = 0; i < 32; i += 8)
        tile[ty + i][tx] = W[(size_t)(kb + ty + i) * N + nb + tx];
    __syncthreads();
#pragma unroll
    for (int i = 0; i < 32; i += 8)
        WT[(size_t)(nb + ty + i) * K + kb + tx] = f2bf(tile[tx][ty + i]);
}

// ---------------------------------------------------------------------------
// ffn1 GEMM: C = relu(A @ BT^T + bias) -> bf16. 128x128 tile.
// global_load_lds staging + LDS-bounce vectorized epilogue.
// ---------------------------------------------------------------------------
__global__ __launch_bounds__(256) void ffn1_gemm(
        const unsigned short* __restrict__ A,
        const unsigned short* __restrict__ BT, const float* __restrict__ bias,
        unsigned short* __restrict__ Cv, int N, int K, int lda, int ldb) {
    __shared__ unsigned short smraw[17408];   // staging (2x8192) / bounce [128][136]
    auto Ash = (unsigned short (*)[128][32])smraw;
    auto Bsh = (unsigned short (*)[128][32])(smraw + 8192);

    int rowt, colt;
    swz85(blockIdx.x, N >> 7, rowt, colt);
    const int row0 = rowt * 128, col0 = colt * 128;

    const int t = threadIdx.x;
    const int wave = t >> 6, lane = t & 63;
    const int wr = wave >> 1, wc = wave & 1;
    const int lrow = lane & 15, quad = lane >> 4;
    const int sr = lane >> 2, sc = (lane & 3) * 8;

    const unsigned short* Ab = A + (size_t)row0 * lda;
    const unsigned short* Bb = BT + (size_t)col0 * ldb;

    f32x4 acc[4][4];
#pragma unroll
    for (int i = 0; i < 4; i++)
#pragma unroll
        for (int j = 0; j < 4; j++) acc[i][j] = (f32x4){0.f, 0.f, 0.f, 0.f};

    auto stage = [&](int buf, int kb) {
#pragma unroll
        for (int j = 0; j < 2; j++) {
            const int r = wave * 32 + j * 16;
            gl16(Ab + (size_t)(r + sr) * lda + kb + sc, &Ash[buf][r][0]);
            gl16(Bb + (size_t)(r + sr) * ldb + kb + sc, &Bsh[buf][r][0]);
        }
    };

    stage(0, 0);
    int i = 0;
    for (int kb = 0; kb < K; kb += 32, ++i) {
        __syncthreads();
        if (kb + 32 < K) stage((i + 1) & 1, kb + 32);
        const int cf = i & 1;
        short8 af[4], bfr[4];
#pragma unroll
        for (int mt = 0; mt < 4; mt++)
            af[mt] = *(const short8*)&Ash[cf][wr * 64 + mt * 16 + lrow][quad * 8];
#pragma unroll
        for (int nt = 0; nt < 4; nt++)
            bfr[nt] = *(const short8*)&Bsh[cf][wc * 64 + nt * 16 + lrow][quad * 8];
#pragma unroll
        for (int mt = 0; mt < 4; mt++)
#pragma unroll
            for (int nt = 0; nt < 4; nt++)
                acc[mt][nt] = __builtin_amdgcn_mfma_f32_16x16x32_bf16(
                    af[mt], bfr[nt], acc[mt][nt], 0, 0, 0);
    }

    __syncthreads();                      // staging dead; reuse as bounce
    auto bounce = (unsigned short (*)[136])smraw;
#pragma unroll
    for (int nt = 0; nt < 4; nt++) {
        const int cl = wc * 64 + nt * 16 + lrow;
        const float bv = bias[col0 + cl];
#pragma unroll
        for (int mt = 0; mt < 4; mt++) {
            f32x4 a = acc[mt][nt];
#pragma unroll
            for (int r = 0; r < 4; r++)
                bounce[wr * 64 + mt * 16 + quad * 4 + r][cl] = f2bf(fmaxf(a[r] + bv, 0.f));
        }
    }
    __syncthreads();
#pragma unroll
    for (int pass = 0; pass < 8; pass++) {
        const int rl = pass * 16 + (t >> 4), ch = t & 15;
        *(uint4*)&Cv[(size_t)(row0 + rl) * N + col0 + ch * 8] =
            *(const uint4*)&bounce[rl][ch * 8];
    }
}

// ---------------------------------------------------------------------------
// Split-K GEMM (N=256), bf16 partials. LDS-bounce vectorized epilogue.
// ---------------------------------------------------------------------------
template <int NZ>
__global__ __launch_bounds__(256) void splitk_gemm(
        const unsigned short* __restrict__ A, const unsigned short* __restrict__ BT,
        unsigned short* __restrict__ part, int KC, int lda, int ldb) {
    __shared__ unsigned short smraw[17408];
    auto Ash = (unsigned short (*)[128][32])smraw;
    auto Bsh = (unsigned short (*)[128][32])(smraw + 8192);

    int rowt, cc;
    swz85(blockIdx.x, 2 * NZ, rowt, cc);
    const int row0 = rowt * 128;
    const int col0 = (cc & 1) * 128;
    const int z = cc >> 1;
    const int koff = z * KC;
    unsigned short* __restrict__ C = part + (size_t)z * MROWS * 256;

    const int t = threadIdx.x;
    const int wave = t >> 6, lane = t & 63;
    const int wr = wave >> 1, wc = wave & 1;
    const int lrow = lane & 15, quad = lane >> 4;
    const int sr = lane >> 2, sc = (lane & 3) * 8;

    const unsigned short* Ab = A + (size_t)row0 * lda + koff;
    const unsigned short* Bb = BT + (size_t)col0 * ldb + koff;

    f32x4 acc[4][4];
#pragma unroll
    for (int i = 0; i < 4; i++)
#pragma unroll
        for (int j = 0; j < 4; j++) acc[i][j] = (f32x4){0.f, 0.f, 0.f, 0.f};

    auto stage = [&](int buf, int kb) {
#pragma unroll
        for (int j = 0; j < 2; j++) {
            const int r = wave * 32 + j * 16;
            gl16(Ab + (size_t)(r + sr) * lda + kb + sc, &Ash[buf][r][0]);
            gl16(Bb + (size_t)(r + sr) * ldb + kb + sc, &Bsh[buf][r][0]);
        }
    };

    stage(0, 0);
    int i = 0;
    for (int kb = 0; kb < KC; kb += 32, ++i) {
        __syncthreads();
        if (kb + 32 < KC) stage((i + 1) & 1, kb + 32);
        const int cf = i & 1;
        short8 af[4], bfr[4];
#pragma unroll
        for (int mt = 0; mt < 4; mt++)
            af[mt] = *(const short8*)&Ash[cf][wr * 64 + mt * 16 + lrow][quad * 8];
#pragma unroll
        for (int nt = 0; nt < 4; nt++)
            bfr[nt] = *(const short8*)&Bsh[cf][wc * 64 + nt * 16 + lrow][quad * 8];
#pragma unroll
        for (int mt = 0; mt < 4; mt++)
#pragma unroll
            for (int nt = 0; nt < 4; nt++)
                acc[mt][nt] = __builtin_amdgcn_mfma_f32_16x16x32_bf16(
                    af[mt], bfr[nt], acc[mt][nt], 0, 0, 0);
    }

    __syncthreads();
    auto bounce = (unsigned short (*)[136])smraw;
#pragma unroll
    for (int nt = 0; nt < 4; nt++) {
        const int cl = wc * 64 + nt * 16 + lrow;
#pragma unroll
        for (int mt = 0; mt < 4; mt++) {
            f32x4 a = acc[mt][nt];
#pragma unroll
            for (int r = 0; r < 4; r++)
                bounce[wr * 64 + mt * 16 + quad * 4 + r][cl] = f2bf(a[r]);
        }
    }
    __syncthreads();
#pragma unroll
    for (int pass = 0; pass < 8; pass++) {
        const int rl = pass * 16 + (t >> 4), ch = t & 15;
        *(uint4*)&C[(size_t)(row0 + rl) * 256 + col0 + ch * 8] =
            *(const uint4*)&bounce[rl][ch * 8];
    }
}

// ---------------------------------------------------------------------------
// Fused GEMM + bias + residual + LayerNorm (K=256 proj). Output: bf16 only.
// ---------------------------------------------------------------------------
__global__ __launch_bounds__(256) void gemm_ln(
        const unsigned short* __restrict__ A, const unsigned short* __restrict__ BT,
        const float* __restrict__ bias, const float* __restrict__ rsd,
        const float* __restrict__ g, const float* __restrict__ be,
        unsigned short* __restrict__ out16, int K) {
    __shared__ unsigned short Ash[2][32][32];
    __shared__ unsigned short Bsh[2][256][32];
    __shared__ float red1[4][32], red2[4][32];

    const int row0 = blockIdx.x * 32;
    const int t = threadIdx.x;
    const int wave = t >> 6, lane = t & 63;
    const int lrow = lane & 15, quad = lane >> 4;
    const int sr = lane >> 2, sc = (lane & 3) * 8;

    f32x4 acc[2][4];
#pragma unroll
    for (int i = 0; i < 2; i++)
#pragma unroll
        for (int j = 0; j < 4; j++) acc[i][j] = (f32x4){0.f, 0.f, 0.f, 0.f};

    auto stage = [&](int buf, int kb) {
#pragma unroll
        for (int j = 0; j < 4; j++) {
            const int r = wave * 64 + j * 16;
            gl16(BT + (size_t)(r + sr) * K + kb + sc, &Bsh[buf][r][0]);
        }
        if (wave < 2) {
            const int r = wave * 16;
            gl16(A + (size_t)(row0 + r + sr) * K + kb + sc, &Ash[buf][r][0]);
        }
    };

    stage(0, 0);
    int it = 0;
    for (int kb = 0; kb < K; kb += 32, ++it) {
        __syncthreads();
        if (kb + 32 < K) stage((it + 1) & 1, kb + 32);
        const int cf = it & 1;
        short8 af[2], bfr[4];
#pragma unroll
        for (int mt = 0; mt < 2; mt++)
            af[mt] = *(const short8*)&Ash[cf][mt * 16 + lrow][quad * 8];
#pragma unroll
        for (int nt = 0; nt < 4; nt++)
            bfr[nt] = *(const short8*)&Bsh[cf][wave * 64 + nt * 16 + lrow][quad * 8];
#pragma unroll
        for (int mt = 0; mt < 2; mt++)
#pragma unroll
            for (int nt = 0; nt < 4; nt++)
                acc[mt][nt] = __builtin_amdgcn_mfma_f32_16x16x32_bf16(
                    af[mt], bfr[nt], acc[mt][nt], 0, 0, 0);
    }

    float gv[4], bev[4], bv[4];
#pragma unroll
    for (int nt = 0; nt < 4; nt++) {
        const int col = wave * 64 + nt * 16 + lrow;
        bv[nt] = bias[col];
        gv[nt] = g[col];
        bev[nt] = be[col];
    }

    float v[2][4][4];
#pragma unroll
    for (int mt = 0; mt < 2; mt++)
#pragma unroll
        for (int r = 0; r < 4; r++) {
            const int row = row0 + mt * 16 + quad * 4 + r;
#pragma unroll
            for (int nt = 0; nt < 4; nt++) {
                const int col = wave * 64 + nt * 16 + lrow;
                v[mt][nt][r] = acc[mt][nt][r] + bv[nt] + rsd[(size_t)row * 256 + col];
            }
        }

#pragma unroll
    for (int mt = 0; mt < 2; mt++)
#pragma unroll
        for (int r = 0; r < 4; r++) {
            float s1 = v[mt][0][r] + v[mt][1][r] + v[mt][2][r] + v[mt][3][r];
            float s2 = v[mt][0][r] * v[mt][0][r] + v[mt][1][r] * v[mt][1][r] +
                       v[mt][2][r] * v[mt][2][r] + v[mt][3][r] * v[mt][3][r];
#pragma unroll
            for (int o = 1; o < 16; o <<= 1) {
                s1 += __shfl_xor(s1, o, 16);
                s2 += __shfl_xor(s2, o, 16);
            }
            if (lrow == 0) {
                const int rr = mt * 16 + quad * 4 + r;
                red1[wave][rr] = s1;
                red2[wave][rr] = s2;
            }
        }
    __syncthreads();

#pragma unroll
    for (int mt = 0; mt < 2; mt++)
#pragma unroll
        for (int r = 0; r < 4; r++) {
            const int rr = mt * 16 + quad * 4 + r;
            const float su = red1[0][rr] + red1[1][rr] + red1[2][rr] + red1[3][rr];
            const float sq = red2[0][rr] + red2[1][rr] + red2[2][rr] + red2[3][rr];
            const float mean = su * (1.0f / 256.0f);
            const float var = fmaxf(sq * (1.0f / 256.0f) - mean * mean, 0.f);
            const float rstd = rsqrtf(var + 1e-5f);
            const size_t rowoff = (size_t)(row0 + rr) * 256;
#pragma unroll
            for (int nt = 0; nt < 4; nt++) {
                const int col = wave * 64 + nt * 16 + lrow;
                const float o = (v[mt][nt][r] - mean) * rstd * gv[nt] + bev[nt];
                out16[rowoff + col] = f2bf(o);
            }
        }
}

// ---------------------------------------------------------------------------
// Merged value+query GEMM (N=640): A = fp32 src(+pos for col0>=256) packed to
// bf16 in regs (padded LDS); B via global_load_lds; LDS-bounce epilogue.
// ---------------------------------------------------------------------------
__global__ __launch_bounds__(256) void qv_gemm(
        const float* __restrict__ src, const float* __restrict__ pos,
        const unsigned short* __restrict__ BT, const float* __restrict__ bias,
        unsigned short* __restrict__ val, unsigned short* __restrict__ qout16) {
    __shared__ unsigned short smraw[18432];  // Ash 2*128*40 | Bsh 2*128*32 ; bounce reuse
    auto Ash = (unsigned short (*)[128][40])smraw;
    auto Bsh = (unsigned short (*)[128][32])(smraw + 10240);

    int rowt, colt;
    swz85(blockIdx.x, 5, rowt, colt);
    const int row0 = rowt * 128, col0 = colt * 128;
    const bool addp = (col0 >= 256);

    const int t = threadIdx.x;
    const int wave = t >> 6, lane = t & 63;
    const int wr = wave >> 1, wc = wave & 1;
    const int lrow = lane & 15, quad = lane >> 4;
    const int srow = t >> 1;
    const int cb = (t & 1) * 16;
    const int sr = lane >> 2, sc = (lane & 3) * 8;

    const float* ap = src + (size_t)(row0 + srow) * 256 + cb;
    const float* pp = pos + (size_t)(row0 + srow) * 256 + cb;
    const unsigned short* Bb = BT + (size_t)col0 * 256;

    f32x4 acc[4][4];
#pragma unroll
    for (int i = 0; i < 4; i++)
#pragma unroll
        for (int j = 0; j < 4; j++) acc[i][j] = (f32x4){0.f, 0.f, 0.f, 0.f};

    float4 fa[4]; float4 fp[4];
    auto packA = [&](int buf) {
        float4 f0 = fa[0], f1 = fa[1], f2 = fa[2], f3 = fa[3];
        if (addp) {
            f0.x += fp[0].x; f0.y += fp[0].y; f0.z += fp[0].z; f0.w += fp[0].w;
            f1.x += fp[1].x; f1.y += fp[1].y; f1.z += fp[1].z; f1.w += fp[1].w;
            f2.x += fp[2].x; f2.y += fp[2].y; f2.z += fp[2].z; f2.w += fp[2].w;
            f3.x += fp[3].x; f3.y += fp[3].y; f3.z += fp[3].z; f3.w += fp[3].w;
        }
        uint4 u0 = make_uint4(pack2(f0.x, f0.y), pack2(f0.z, f0.w),
                              pack2(f1.x, f1.y), pack2(f1.z, f1.w));
        uint4 u1 = make_uint4(pack2(f2.x, f2.y), pack2(f2.z, f2.w),
                              pack2(f3.x, f3.y), pack2(f3.z, f3.w));
        *(uint4*)&Ash[buf][srow][cb + 0] = u0;
        *(uint4*)&Ash[buf][srow][cb + 8] = u1;
    };
    auto loadA = [&](int kb) {
#pragma unroll
        for (int j = 0; j < 4; j++) fa[j] = *(const float4*)(ap + kb + 4 * j);
        if (addp) {
#pragma unroll
            for (int j = 0; j < 4; j++) fp[j] = *(const float4*)(pp + kb + 4 * j);
        }
    };
    auto stageB = [&](int buf, int kb) {
#pragma unroll
        for (int j = 0; j < 2; j++) {
            const int r = wave * 32 + j * 16;
            gl16(Bb + (size_t)(r + sr) * 256 + kb + sc, &Bsh[buf][r][0]);
        }
    };

    loadA(0);
    packA(0);
    stageB(0, 0);
    loadA(32);

    int i = 0;
    for (int kb = 0; kb < 256; kb += 32, ++i) {
        __syncthreads();
        if (kb + 32 < 256) {
            stageB((i + 1) & 1, kb + 32);
            packA((i + 1) & 1);
            if (kb + 64 < 256) loadA(kb + 64);
        }
        const int cf = i & 1;
        short8 af[4], bfr[4];
#pragma unroll
        for (int mt = 0; mt < 4; mt++)
            af[mt] = *(const short8*)&Ash[cf][wr * 64 + mt * 16 + lrow][quad * 8];
#pragma unroll
        for (int nt = 0; nt < 4; nt++)
            bfr[nt] = *(const short8*)&Bsh[cf][wc * 64 + nt * 16 + lrow][quad * 8];
#pragma unroll
        for (int mt = 0; mt < 4; mt++)
#pragma unroll
            for (int nt = 0; nt < 4; nt++)
                acc[mt][nt] = __builtin_amdgcn_mfma_f32_16x16x32_bf16(
                    af[mt], bfr[nt], acc[mt][nt], 0, 0, 0);
    }

    __syncthreads();
    auto bounce = (unsigned short (*)[136])smraw;
#pragma unroll
    for (int nt = 0; nt < 4; nt++) {
        const int cl = wc * 64 + nt * 16 + lrow;
        const float bv = bias[col0 + cl];
#pragma unroll
        for (int mt = 0; mt < 4; mt++) {
            f32x4 a = acc[mt][nt];
#pragma unroll
            for (int r = 0; r < 4; r++)
                bounce[wr * 64 + mt * 16 + quad * 4 + r][cl] = f2bf(a[r] + bv);
        }
    }
    __syncthreads();
    unsigned short* Cp; int ldc, c0;
    if (col0 < 256) { Cp = val;    ldc = 256; c0 = col0; }
    else            { Cp = qout16; ldc = 384; c0 = col0 - 256; }
#pragma unroll
    for (int pass = 0; pass < 8; pass++) {
        const int rl = pass * 16 + (t >> 4), ch = t & 15;
        *(uint4*)&Cp[(size_t)(row0 + rl) * ldc + c0 + ch * 8] =
            *(const uint4*)&bounce[rl][ch * 8];
    }
}

// ---------------------------------------------------------------------------
// Sampler: 4 queries per block. Phase 1: 256 threads compute idx/weights for
// 4x128 (h,p) slots (2 per thread). Phase 2: 64 lanes per query, 4 channels
// per lane, 8-byte gathers (half the gather instructions of the 2-ch layout).
// FFN weight-transpose blocks ride in the same launch.
// ---------------------------------------------------------------------------
__global__ void sampler(const unsigned short* __restrict__ val,
                        const unsigned short* __restrict__ qout16,
                        unsigned short* __restrict__ out,
                        const float* __restrict__ w_out, const float* __restrict__ w1,
                        const float* __restrict__ w2,
                        unsigned short* __restrict__ woT, unsigned short* __restrict__ w1T,
                        unsigned short* __restrict__ w2T) {
    __shared__ __align__(16) int   sIdx[4][128][4];
    __shared__ __align__(16) float sW[4][128][4];
    __shared__ float tileT[32][33];
    const int t = threadIdx.x;

    if (blockIdx.x >= MROWS / 4) {
        // weight transpose: 64 (w_out) + 512 (w1) + 512 (w2) blocks
        const int bk = (int)blockIdx.x - MROWS / 4;
        const float* W; unsigned short* WT; int K, N, tid;
        if (bk < 64)       { W = w_out; WT = woT;  K = 256;  N = 256;  tid = bk; }
        else if (bk < 576) { W = w1;    WT = w1T;  K = 256;  N = 2048; tid = bk - 64; }
        else               { W = w2;    WT = w2T;  K = 2048; N = 256;  tid = bk - 576; }
        const int ntx = N >> 5;
        const int nb = (tid % ntx) * 32, kb = (tid / ntx) * 32;
        const int tx = t & 31, ty = t >> 5;
#pragma unroll
        for (int i = 0; i < 32; i += 8)
            tileT[ty + i][tx] = W[(size_t)(kb + ty + i) * N + nb + tx];
        __syncthreads();
#pragma unroll
        for (int i = 0; i < 32; i += 8)
            WT[(size_t)(nb + ty + i) * K + kb + tx] = f2bf(tileT[tx][ty + i]);
        return;
    }

    const int pair = t & 127;            // (h,p) slot
    const int qsel = t >> 7;
    const int h1 = pair >> 4, p1 = pair & 15;
    const int lvl = p1 >> 2;

#pragma unroll
    for (int j = 0; j < 2; j++) {
        const int ql = qsel + 2 * j;
        const int bq = (int)blockIdx.x * 4 + ql;
        const int b = bq / LEN, q = bq % LEN;

        float refx, refy;
        if (q < 4096) {
            int rq = q >> 6, cq = q & 63;
            refx = (cq + 0.5f) * (1.0f / 64.0f);
            refy = (rq + 0.5f) * (1.0f / 64.0f);
        } else if (q < 5120) {
            int qq = q - 4096;
            int rq = qq >> 5, cq = qq & 31;
            refx = (cq + 0.5f) * (1.0f / 32.0f);
            refy = (rq + 0.5f) * (1.0f / 32.0f);
        } else if (q < 5376) {
            int qq = q - 5120;
            int rq = qq >> 4, cq = qq & 15;
            refx = (cq + 0.5f) * (1.0f / 16.0f);
            refy = (rq + 0.5f) * (1.0f / 16.0f);
        } else {
            int qq = q - 5376;
            int rq = qq >> 3, cq = qq & 7;
            refx = (cq + 0.5f) * (1.0f / 8.0f);
            refy = (rq + 0.5f) * (1.0f / 8.0f);
        }

        float lv = bf2f(qout16[(size_t)bq * 384 + 256 + pair]);
        float mx = lv;
#pragma unroll
        for (int o = 1; o < 16; o <<= 1) mx = fmaxf(mx, __shfl_xor(mx, o, 16));
        float e = expf(lv - mx);
        float s = e;
#pragma unroll
        for (int o = 1; o < 16; o <<= 1) s += __shfl_xor(s, o, 16);
        const float aw = e / s;

        const uint32 opair = *(const uint32*)&qout16[(size_t)bq * 384 + h1 * 32 + p1 * 2];
        const float ox = bf2f((unsigned short)opair);
        const float oy = bf2f((unsigned short)(opair >> 16));

        const int LST[4] = {0, 4096, 5120, 5376};
        const int WW = 64 >> lvl;
        const float rw = 1.0f / (float)WW;

        float x = (refx + ox * rw) * (float)WW - 0.5f;
        float y = (refy + oy * rw) * (float)WW - 0.5f;
        float x0f = floorf(x), y0f = floorf(y);
        float dx = x - x0f, dy = y - y0f;
        int x0 = (int)x0f, y0 = (int)y0f;

        const int base = (b * LEN + LST[lvl]) * 256 + h1 * 32;
        int xs[2] = {x0, x0 + 1}, ys[2] = {y0, y0 + 1};
        float wx[2] = {1.f - dx, dx}, wy[2] = {1.f - dy, dy};
        int ic[4]; float wc4[4];
#pragma unroll
        for (int cy = 0; cy < 2; cy++)
#pragma unroll
            for (int cx = 0; cx < 2; cx++) {
                int xi = xs[cx], yi = ys[cy];
                bool vld = (xi >= 0) && (xi < WW) && (yi >= 0) && (yi < WW);
                int xc = min(max(xi, 0), WW - 1);
                int yc = min(max(yi, 0), WW - 1);
                ic[cy * 2 + cx] = base + (yc * WW + xc) * 256;
                wc4[cy * 2 + cx] = vld ? wx[cx] * wy[cy] * aw : 0.f;
            }
        *(int4*)&sIdx[ql][pair][0] = make_int4(ic[0], ic[1], ic[2], ic[3]);
        *(float4*)&sW[ql][pair][0] = make_float4(wc4[0], wc4[1], wc4[2], wc4[3]);
    }
    __syncthreads();

    const int g = t >> 6;                 // query within block
    const int l6 = t & 63;
    const int h = l6 >> 3;                // 8 lanes per head
    const int c4 = (l6 & 7) * 4;          // 4 channels per lane
    const int bq = (int)blockIdx.x * 4 + g;
    const unsigned short* vald = val + c4;
    float a0 = 0.f, a1 = 0.f, a2 = 0.f, a3 = 0.f;
#pragma unroll 4
    for (int p = 0; p < 16; p++) {
        const int r = h * 16 + p;
        int4 iv = *(const int4*)&sIdx[g][r][0];
        float4 wv = *(const float4*)&sW[g][r][0];
        ushort4 u0 = *(const ushort4*)(vald + iv.x);
        ushort4 u1 = *(const ushort4*)(vald + iv.y);
        ushort4 u2 = *(const ushort4*)(vald + iv.z);
        ushort4 u3 = *(const ushort4*)(vald + iv.w);
        a0 += bf2f(u0.x) * wv.x + bf2f(u1.x) * wv.y + bf2f(u2.x) * wv.z + bf2f(u3.x) * wv.w;
        a1 += bf2f(u0.y) * wv.x + bf2f(u1.y) * wv.y + bf2f(u2.y) * wv.z + bf2f(u3.y) * wv.w;
        a2 += bf2f(u0.z) * wv.x + bf2f(u1.z) * wv.y + bf2f(u2.z) * wv.z + bf2f(u3.z) * wv.w;
        a3 += bf2f(u0.w) * wv.x + bf2f(u1.w) * wv.y + bf2f(u2.w) * wv.z + bf2f(u3.w) * wv.w;
    }
    uint2 o2;
    o2.x = pack2(a0, a1);
    o2.y = pack2(a2, a3);
    *(uint2*)&out[(size_t)bq * D + h * HD + c4] = o2;
}

// ---------------------------------------------------------------------------
// Final LN, wave-per-row: out = LN(sum_z part16[z] + bias + rsd16) * g + be.
// ---------------------------------------------------------------------------
__global__ void add_ln4(const unsigned short* __restrict__ part16,
                        const float* __restrict__ bias,
                        const unsigned short* __restrict__ rsd16,
                        const float* __restrict__ g, const float* __restrict__ be,
                        float* __restrict__ out) {
    const int wave = threadIdx.x >> 6, lane = threadIdx.x & 63;
    const int row = blockIdx.x * 4 + wave;
    const int c0 = lane * 4;
    const size_t i = (size_t)row * 256 + c0;

    float v[4];
    {
        ushort4 r = *(const ushort4*)&rsd16[i];
        float4 bv = *(const float4*)&bias[c0];
        v[0] = bf2f(r.x) + bv.x; v[1] = bf2f(r.y) + bv.y;
        v[2] = bf2f(r.z) + bv.z; v[3] = bf2f(r.w) + bv.w;
    }
#pragma unroll
    for (int z = 0; z < 4; z++) {
        ushort4 p = *(const ushort4*)&part16[(size_t)z * MROWS * 256 + i];
        v[0] += bf2f(p.x); v[1] += bf2f(p.y); v[2] += bf2f(p.z); v[3] += bf2f(p.w);
    }
    float s1 = v[0] + v[1] + v[2] + v[3];
    float s2 = v[0] * v[0] + v[1] * v[1] + v[2] * v[2] + v[3] * v[3];
#pragma unroll
    for (int o = 32; o > 0; o >>= 1) {
        s1 += __shfl_xor(s1, o, 64);
        s2 += __shfl_xor(s2, o, 64);
    }
    const float mean = s1 * (1.0f / 256.0f);
    const float var = fmaxf(s2 * (1.0f / 256.0f) - mean * mean, 0.f);
    const float rstd = rsqrtf(var + 1e-5f);

    float4 gv = *(const float4*)&g[c0];
    float4 bev = *(const float4*)&be[c0];
    float4 o4;
    o4.x = (v[0] - mean) * rstd * gv.x + bev.x;
    o4.y = (v[1] - mean) * rstd * gv.y + bev.y;
    o4.z = (v[2] - mean) * rstd * gv.z + bev.z;
    o4.w = (v[3] - mean) * rstd * gv.w + bev.w;
    *(float4*)&out[i] = o4;
}

// ---------------------------------------------------------------------------
extern "C" void kernel_launch(void* const* d_in, const int* in_sizes, int n_in,
                              void* d_out, int out_size, void* d_ws, size_t ws_size,
                              hipStream_t stream) {
    const float* src     = (const float*)d_in[0];
    const float* pos     = (const float*)d_in[1];
    const float* w_value = (const float*)d_in[4];
    const float* b_value = (const float*)d_in[5];
    const float* w_off   = (const float*)d_in[6];
    const float* b_off   = (const float*)d_in[7];
    const float* w_attn  = (const float*)d_in[8];
    const float* b_attn  = (const float*)d_in[9];
    const float* w_out   = (const float*)d_in[10];
    const float* b_out   = (const float*)d_in[11];
    const float* w1      = (const float*)d_in[12];
    const float* b1      = (const float*)d_in[13];
    const float* w2      = (const float*)d_in[14];
    const float* b2      = (const float*)d_in[15];
    const float* g1      = (const float*)d_in[16];
    const float* be1     = (const float*)d_in[17];
    const float* g2      = (const float*)d_in[18];
    const float* be2     = (const float*)d_in[19];
    float* out = (float*)d_out;

    // ---- workspace layout ----
    size_t off = 0;
    auto alloc = [&](size_t bytes) -> char* {
        char* p = (char*)d_ws + off;
        off += (bytes + 255) & ~(size_t)255;
        return p;
    };
    unsigned short* wqvT = (unsigned short*)alloc((size_t)640 * 256 * 2);
    unsigned short* woT  = (unsigned short*)alloc(256 * 256 * 2);
    unsigned short* w1T  = (unsigned short*)alloc((size_t)2048 * 256 * 2);
    unsigned short* w2T  = (unsigned short*)alloc((size_t)256 * 2048 * 2);
    float* bqv           = (float*)alloc(640 * 4);

    unsigned short* qout = (unsigned short*)alloc((size_t)MROWS * 384 * 2);
    unsigned short* val  = (unsigned short*)alloc((size_t)MROWS * 256 * 2);
    unsigned short* attn = (unsigned short*)alloc((size_t)MROWS * 256 * 2);
    unsigned short* hb   = (unsigned short*)alloc((size_t)MROWS * 2048 * 2);
    unsigned short* xb16 = (unsigned short*)alloc((size_t)MROWS * 256 * 2);
    unsigned short* part = (unsigned short*)alloc((size_t)4 * MROWS * 256 * 2);

    // ---- small prep (wqv transposes + bias) ----
    prep_a<<<161, 256, 0, stream>>>(w_value, w_off, w_attn, b_value, b_off, b_attn,
                                    wqvT, bqv);

    // ---- attention ----
    qv_gemm<<<425, 256, 0, stream>>>(src, pos, wqvT, bqv, val, qout);
    // sampler (4 queries/block) + appended FFN weight transposes (1088 blocks)
    sampler<<<MROWS / 4 + 1088, 256, 0, stream>>>(val, qout, attn,
                                                  w_out, w1, w2, woT, w1T, w2T);
    // x = LN(attn @ w_out + b_out + src) -> xb16   (fused, K=256)
    gemm_ln<<<340, 256, 0, stream>>>(attn, woT, b_out, src, g1, be1, xb16, 256);

    // ---- FFN ----
    ffn1_gemm<<<1360, 256, 0, stream>>>(xb16, w1T, b1, hb, 2048, 256, 256, 256);
    splitk_gemm<4><<<680, 256, 0, stream>>>(hb, w2T, part, 512, 2048, 2048);
    add_ln4<<<MROWS / 4, 256, 0, stream>>>(part, b2, xb16, g2, be2, out);
}

// Round 4
// 194.812 us; speedup vs baseline: 1.0480x; 1.0480x over previous
//
#include <hip/hip_runtime.h>
#include <math.h>

#define D 256
#define NH 8
#define NL 4
#define NP 4
#define DFF 2048
#define HD 32
#define BB 2
#define LEN 5440
#define MROWS (BB * LEN)   // 10880 = 85*128 = 340*32 = 2720*4

typedef __attribute__((ext_vector_type(8))) short short8;
typedef __attribute__((ext_vector_type(4))) float f32x4;
typedef unsigned int uint32;

__device__ __forceinline__ unsigned short f2bf(float f) {
    uint32 u = __float_as_uint(f);
    u += 0x7FFF + ((u >> 16) & 1);           // round-to-nearest-even
    return (unsigned short)(u >> 16);
}
__device__ __forceinline__ float bf2f(unsigned short h) {
    return __uint_as_float(((uint32)h) << 16);
}
__device__ __forceinline__ uint32 pack2(float a, float b) {
    return (uint32)f2bf(a) | ((uint32)f2bf(b) << 16);
}
// accumulate 8 bf16 channels from a 16B gather, weighted
__device__ __forceinline__ void acc8(float* a, uint4 u, float w) {
    a[0] += bf2f((unsigned short)u.x) * w; a[1] += bf2f((unsigned short)(u.x >> 16)) * w;
    a[2] += bf2f((unsigned short)u.y) * w; a[3] += bf2f((unsigned short)(u.y >> 16)) * w;
    a[4] += bf2f((unsigned short)u.z) * w; a[5] += bf2f((unsigned short)(u.z >> 16)) * w;
    a[6] += bf2f((unsigned short)u.w) * w; a[7] += bf2f((unsigned short)(u.w >> 16)) * w;
}

// async global->LDS, 16B per lane. LDS dest is wave-uniform base + lane*16.
__device__ __forceinline__ void gl16(const unsigned short* g, unsigned short* l) {
    __builtin_amdgcn_global_load_lds(
        (const __attribute__((address_space(1))) unsigned int*)g,
        (__attribute__((address_space(3))) unsigned int*)l, 16, 0, 0);
}

// XCD-affinity swizzle: 85 row-tiles x ncols col-tiles.
__device__ __forceinline__ void swz85(int b, int ncols, int& row, int& col) {
    const int gsz = ncols << 3;
    const int full = 10 * gsz;
    if (b < full) {
        const int g = b / gsz, idx = b - g * gsz;
        row = (g << 3) + (idx & 7);
        col = idx >> 3;
    } else {
        const int idx = b - full;
        row = 80 + idx % 5;
        col = idx / 5;
    }
}

// ---------------------------------------------------------------------------
// prep_a: wqv transposes (fp32 [KxN] -> bf16 [NxK]) + bias concat. 161 blocks.
// ---------------------------------------------------------------------------
__global__ void prep_a(const float* __restrict__ w_value, const float* __restrict__ w_off,
                       const float* __restrict__ w_attn,
                       const float* __restrict__ b_value, const float* __restrict__ b_off,
                       const float* __restrict__ b_attn,
                       unsigned short* __restrict__ wqvT, float* __restrict__ bqv) {
    __shared__ float tile[32][33];
    const int blk = blockIdx.x;
    const int t = threadIdx.x;
    if (blk >= 160) {
        for (int i = t; i < 640; i += 256)
            bqv[i] = (i < 256) ? b_value[i] : (i < 512 ? b_off[i - 256] : b_attn[i - 512]);
        return;
    }
    const float* W; unsigned short* WT; int N, tid;
    if (blk < 64)       { W = w_value; WT = wqvT;             N = 256; tid = blk; }
    else if (blk < 128) { W = w_off;   WT = wqvT + 256 * 256; N = 256; tid = blk - 64; }
    else                { W = w_attn;  WT = wqvT + 512 * 256; N = 128; tid = blk - 128; }
    const int K = 256;
    const int ntx = N >> 5;
    const int nb = (tid % ntx) * 32, kb = (tid / ntx) * 32;
    const int tx = t & 31, ty = t >> 5;
#pragma unroll
    for (int i = 0; i < 32; i += 8)
        tile[ty + i][tx] = W[(size_t)(kb + ty + i) * N + nb + tx];
    __syncthreads();
#pragma unroll
    for (int i = 0; i < 32; i += 8)
        WT[(size_t)(nb + ty + i) * K + kb + tx] = f2bf(tile[tx][ty + i]);
}

// ---------------------------------------------------------------------------
// ffn1 GEMM: C = relu(A @ BT^T + bias) -> bf16. 128x128 tile.
// global_load_lds staging + LDS-bounce vectorized epilogue.
// ---------------------------------------------------------------------------
__global__ __launch_bounds__(256) void ffn1_gemm(
        const unsigned short* __restrict__ A,
        const unsigned short* __restrict__ BT, const float* __restrict__ bias,
        unsigned short* __restrict__ Cv, int N, int K, int lda, int ldb) {
    __shared__ unsigned short smraw[17408];   // staging (2x8192) / bounce [128][136]
    auto Ash = (unsigned short (*)[128][32])smraw;
    auto Bsh = (unsigned short (*)[128][32])(smraw + 8192);

    int rowt, colt;
    swz85(blockIdx.x, N >> 7, rowt, colt);
    const int row0 = rowt * 128, col0 = colt * 128;

    const int t = threadIdx.x;
    const int wave = t >> 6, lane = t & 63;
    const int wr = wave >> 1, wc = wave & 1;
    const int lrow = lane & 15, quad = lane >> 4;
    const int sr = lane >> 2, sc = (lane & 3) * 8;

    const unsigned short* Ab = A + (size_t)row0 * lda;
    const unsigned short* Bb = BT + (size_t)col0 * ldb;

    f32x4 acc[4][4];
#pragma unroll
    for (int i = 0; i < 4; i++)
#pragma unroll
        for (int j = 0; j < 4; j++) acc[i][j] = (f32x4){0.f, 0.f, 0.f, 0.f};

    auto stage = [&](int buf, int kb) {
#pragma unroll
        for (int j = 0; j < 2; j++) {
            const int r = wave * 32 + j * 16;
            gl16(Ab + (size_t)(r + sr) * lda + kb + sc, &Ash[buf][r][0]);
            gl16(Bb + (size_t)(r + sr) * ldb + kb + sc, &Bsh[buf][r][0]);
        }
    };

    stage(0, 0);
    int i = 0;
    for (int kb = 0; kb < K; kb += 32, ++i) {
        __syncthreads();
        if (kb + 32 < K) stage((i + 1) & 1, kb + 32);
        const int cf = i & 1;
        short8 af[4], bfr[4];
#pragma unroll
        for (int mt = 0; mt < 4; mt++)
            af[mt] = *(const short8*)&Ash[cf][wr * 64 + mt * 16 + lrow][quad * 8];
#pragma unroll
        for (int nt = 0; nt < 4; nt++)
            bfr[nt] = *(const short8*)&Bsh[cf][wc * 64 + nt * 16 + lrow][quad * 8];
#pragma unroll
        for (int mt = 0; mt < 4; mt++)
#pragma unroll
            for (int nt = 0; nt < 4; nt++)
                acc[mt][nt] = __builtin_amdgcn_mfma_f32_16x16x32_bf16(
                    af[mt], bfr[nt], acc[mt][nt], 0, 0, 0);
    }

    __syncthreads();                      // staging dead; reuse as bounce
    auto bounce = (unsigned short (*)[136])smraw;
#pragma unroll
    for (int nt = 0; nt < 4; nt++) {
        const int cl = wc * 64 + nt * 16 + lrow;
        const float bv = bias[col0 + cl];
#pragma unroll
        for (int mt = 0; mt < 4; mt++) {
            f32x4 a = acc[mt][nt];
#pragma unroll
            for (int r = 0; r < 4; r++)
                bounce[wr * 64 + mt * 16 + quad * 4 + r][cl] = f2bf(fmaxf(a[r] + bv, 0.f));
        }
    }
    __syncthreads();
#pragma unroll
    for (int pass = 0; pass < 8; pass++) {
        const int rl = pass * 16 + (t >> 4), ch = t & 15;
        *(uint4*)&Cv[(size_t)(row0 + rl) * N + col0 + ch * 8] =
            *(const uint4*)&bounce[rl][ch * 8];
    }
}

// ---------------------------------------------------------------------------
// Split-K GEMM (N=256), bf16 partials. LDS-bounce vectorized epilogue.
// ---------------------------------------------------------------------------
template <int NZ>
__global__ __launch_bounds__(256) void splitk_gemm(
        const unsigned short* __restrict__ A, const unsigned short* __restrict__ BT,
        unsigned short* __restrict__ part, int KC, int lda, int ldb) {
    __shared__ unsigned short smraw[17408];
    auto Ash = (unsigned short (*)[128][32])smraw;
    auto Bsh = (unsigned short (*)[128][32])(smraw + 8192);

    int rowt, cc;
    swz85(blockIdx.x, 2 * NZ, rowt, cc);
    const int row0 = rowt * 128;
    const int col0 = (cc & 1) * 128;
    const int z = cc >> 1;
    const int koff = z * KC;
    unsigned short* __restrict__ C = part + (size_t)z * MROWS * 256;

    const int t = threadIdx.x;
    const int wave = t >> 6, lane = t & 63;
    const int wr = wave >> 1, wc = wave & 1;
    const int lrow = lane & 15, quad = lane >> 4;
    const int sr = lane >> 2, sc = (lane & 3) * 8;

    const unsigned short* Ab = A + (size_t)row0 * lda + koff;
    const unsigned short* Bb = BT + (size_t)col0 * ldb + koff;

    f32x4 acc[4][4];
#pragma unroll
    for (int i = 0; i < 4; i++)
#pragma unroll
        for (int j = 0; j < 4; j++) acc[i][j] = (f32x4){0.f, 0.f, 0.f, 0.f};

    auto stage = [&](int buf, int kb) {
#pragma unroll
        for (int j = 0; j < 2; j++) {
            const int r = wave * 32 + j * 16;
            gl16(Ab + (size_t)(r + sr) * lda + kb + sc, &Ash[buf][r][0]);
            gl16(Bb + (size_t)(r + sr) * ldb + kb + sc, &Bsh[buf][r][0]);
        }
    };

    stage(0, 0);
    int i = 0;
    for (int kb = 0; kb < KC; kb += 32, ++i) {
        __syncthreads();
        if (kb + 32 < KC) stage((i + 1) & 1, kb + 32);
        const int cf = i & 1;
        short8 af[4], bfr[4];
#pragma unroll
        for (int mt = 0; mt < 4; mt++)
            af[mt] = *(const short8*)&Ash[cf][wr * 64 + mt * 16 + lrow][quad * 8];
#pragma unroll
        for (int nt = 0; nt < 4; nt++)
            bfr[nt] = *(const short8*)&Bsh[cf][wc * 64 + nt * 16 + lrow][quad * 8];
#pragma unroll
        for (int mt = 0; mt < 4; mt++)
#pragma unroll
            for (int nt = 0; nt < 4; nt++)
                acc[mt][nt] = __builtin_amdgcn_mfma_f32_16x16x32_bf16(
                    af[mt], bfr[nt], acc[mt][nt], 0, 0, 0);
    }

    __syncthreads();
    auto bounce = (unsigned short (*)[136])smraw;
#pragma unroll
    for (int nt = 0; nt < 4; nt++) {
        const int cl = wc * 64 + nt * 16 + lrow;
#pragma unroll
        for (int mt = 0; mt < 4; mt++) {
            f32x4 a = acc[mt][nt];
#pragma unroll
            for (int r = 0; r < 4; r++)
                bounce[wr * 64 + mt * 16 + quad * 4 + r][cl] = f2bf(a[r]);
        }
    }
    __syncthreads();
#pragma unroll
    for (int pass = 0; pass < 8; pass++) {
        const int rl = pass * 16 + (t >> 4), ch = t & 15;
        *(uint4*)&C[(size_t)(row0 + rl) * 256 + col0 + ch * 8] =
            *(const uint4*)&bounce[rl][ch * 8];
    }
}

// ---------------------------------------------------------------------------
// Fused GEMM + bias + residual + LayerNorm (K=256 proj). Output: bf16 only.
// ---------------------------------------------------------------------------
__global__ __launch_bounds__(256) void gemm_ln(
        const unsigned short* __restrict__ A, const unsigned short* __restrict__ BT,
        const float* __restrict__ bias, const float* __restrict__ rsd,
        const float* __restrict__ g, const float* __restrict__ be,
        unsigned short* __restrict__ out16, int K) {
    __shared__ unsigned short Ash[2][32][32];
    __shared__ unsigned short Bsh[2][256][32];
    __shared__ float red1[4][32], red2[4][32];

    const int row0 = blockIdx.x * 32;
    const int t = threadIdx.x;
    const int wave = t >> 6, lane = t & 63;
    const int lrow = lane & 15, quad = lane >> 4;
    const int sr = lane >> 2, sc = (lane & 3) * 8;

    f32x4 acc[2][4];
#pragma unroll
    for (int i = 0; i < 2; i++)
#pragma unroll
        for (int j = 0; j < 4; j++) acc[i][j] = (f32x4){0.f, 0.f, 0.f, 0.f};

    auto stage = [&](int buf, int kb) {
#pragma unroll
        for (int j = 0; j < 4; j++) {
            const int r = wave * 64 + j * 16;
            gl16(BT + (size_t)(r + sr) * K + kb + sc, &Bsh[buf][r][0]);
        }
        if (wave < 2) {
            const int r = wave * 16;
            gl16(A + (size_t)(row0 + r + sr) * K + kb + sc, &Ash[buf][r][0]);
        }
    };

    stage(0, 0);
    int it = 0;
    for (int kb = 0; kb < K; kb += 32, ++it) {
        __syncthreads();
        if (kb + 32 < K) stage((it + 1) & 1, kb + 32);
        const int cf = it & 1;
        short8 af[2], bfr[4];
#pragma unroll
        for (int mt = 0; mt < 2; mt++)
            af[mt] = *(const short8*)&Ash[cf][mt * 16 + lrow][quad * 8];
#pragma unroll
        for (int nt = 0; nt < 4; nt++)
            bfr[nt] = *(const short8*)&Bsh[cf][wave * 64 + nt * 16 + lrow][quad * 8];
#pragma unroll
        for (int mt = 0; mt < 2; mt++)
#pragma unroll
            for (int nt = 0; nt < 4; nt++)
                acc[mt][nt] = __builtin_amdgcn_mfma_f32_16x16x32_bf16(
                    af[mt], bfr[nt], acc[mt][nt], 0, 0, 0);
    }

    float gv[4], bev[4], bv[4];
#pragma unroll
    for (int nt = 0; nt < 4; nt++) {
        const int col = wave * 64 + nt * 16 + lrow;
        bv[nt] = bias[col];
        gv[nt] = g[col];
        bev[nt] = be[col];
    }

    float v[2][4][4];
#pragma unroll
    for (int mt = 0; mt < 2; mt++)
#pragma unroll
        for (int r = 0; r < 4; r++) {
            const int row = row0 + mt * 16 + quad * 4 + r;
#pragma unroll
            for (int nt = 0; nt < 4; nt++) {
                const int col = wave * 64 + nt * 16 + lrow;
                v[mt][nt][r] = acc[mt][nt][r] + bv[nt] + rsd[(size_t)row * 256 + col];
            }
        }

#pragma unroll
    for (int mt = 0; mt < 2; mt++)
#pragma unroll
        for (int r = 0; r < 4; r++) {
            float s1 = v[mt][0][r] + v[mt][1][r] + v[mt][2][r] + v[mt][3][r];
            float s2 = v[mt][0][r] * v[mt][0][r] + v[mt][1][r] * v[mt][1][r] +
                       v[mt][2][r] * v[mt][2][r] + v[mt][3][r] * v[mt][3][r];
#pragma unroll
            for (int o = 1; o < 16; o <<= 1) {
                s1 += __shfl_xor(s1, o, 16);
                s2 += __shfl_xor(s2, o, 16);
            }
            if (lrow == 0) {
                const int rr = mt * 16 + quad * 4 + r;
                red1[wave][rr] = s1;
                red2[wave][rr] = s2;
            }
        }
    __syncthreads();

#pragma unroll
    for (int mt = 0; mt < 2; mt++)
#pragma unroll
        for (int r = 0; r < 4; r++) {
            const int rr = mt * 16 + quad * 4 + r;
            const float su = red1[0][rr] + red1[1][rr] + red1[2][rr] + red1[3][rr];
            const float sq = red2[0][rr] + red2[1][rr] + red2[2][rr] + red2[3][rr];
            const float mean = su * (1.0f / 256.0f);
            const float var = fmaxf(sq * (1.0f / 256.0f) - mean * mean, 0.f);
            const float rstd = rsqrtf(var + 1e-5f);
            const size_t rowoff = (size_t)(row0 + rr) * 256;
#pragma unroll
            for (int nt = 0; nt < 4; nt++) {
                const int col = wave * 64 + nt * 16 + lrow;
                const float o = (v[mt][nt][r] - mean) * rstd * gv[nt] + bev[nt];
                out16[rowoff + col] = f2bf(o);
            }
        }
}

// ---------------------------------------------------------------------------
// Merged value+query GEMM (N=640): A = fp32 src(+pos for col0>=256) packed to
// bf16 in regs (padded LDS); B via global_load_lds; LDS-bounce epilogue.
// ---------------------------------------------------------------------------
__global__ __launch_bounds__(256) void qv_gemm(
        const float* __restrict__ src, const float* __restrict__ pos,
        const unsigned short* __restrict__ BT, const float* __restrict__ bias,
        unsigned short* __restrict__ val, unsigned short* __restrict__ qout16) {
    __shared__ unsigned short smraw[18432];  // Ash 2*128*40 | Bsh 2*128*32 ; bounce reuse
    auto Ash = (unsigned short (*)[128][40])smraw;
    auto Bsh = (unsigned short (*)[128][32])(smraw + 10240);

    int rowt, colt;
    swz85(blockIdx.x, 5, rowt, colt);
    const int row0 = rowt * 128, col0 = colt * 128;
    const bool addp = (col0 >= 256);

    const int t = threadIdx.x;
    const int wave = t >> 6, lane = t & 63;
    const int wr = wave >> 1, wc = wave & 1;
    const int lrow = lane & 15, quad = lane >> 4;
    const int srow = t >> 1;
    const int cb = (t & 1) * 16;
    const int sr = lane >> 2, sc = (lane & 3) * 8;

    const float* ap = src + (size_t)(row0 + srow) * 256 + cb;
    const float* pp = pos + (size_t)(row0 + srow) * 256 + cb;
    const unsigned short* Bb = BT + (size_t)col0 * 256;

    f32x4 acc[4][4];
#pragma unroll
    for (int i = 0; i < 4; i++)
#pragma unroll
        for (int j = 0; j < 4; j++) acc[i][j] = (f32x4){0.f, 0.f, 0.f, 0.f};

    float4 fa[4]; float4 fp[4];
    auto packA = [&](int buf) {
        float4 f0 = fa[0], f1 = fa[1], f2 = fa[2], f3 = fa[3];
        if (addp) {
            f0.x += fp[0].x; f0.y += fp[0].y; f0.z += fp[0].z; f0.w += fp[0].w;
            f1.x += fp[1].x; f1.y += fp[1].y; f1.z += fp[1].z; f1.w += fp[1].w;
            f2.x += fp[2].x; f2.y += fp[2].y; f2.z += fp[2].z; f2.w += fp[2].w;
            f3.x += fp[3].x; f3.y += fp[3].y; f3.z += fp[3].z; f3.w += fp[3].w;
        }
        uint4 u0 = make_uint4(pack2(f0.x, f0.y), pack2(f0.z, f0.w),
                              pack2(f1.x, f1.y), pack2(f1.z, f1.w));
        uint4 u1 = make_uint4(pack2(f2.x, f2.y), pack2(f2.z, f2.w),
                              pack2(f3.x, f3.y), pack2(f3.z, f3.w));
        *(uint4*)&Ash[buf][srow][cb + 0] = u0;
        *(uint4*)&Ash[buf][srow][cb + 8] = u1;
    };
    auto loadA = [&](int kb) {
#pragma unroll
        for (int j = 0; j < 4; j++) fa[j] = *(const float4*)(ap + kb + 4 * j);
        if (addp) {
#pragma unroll
            for (int j = 0; j < 4; j++) fp[j] = *(const float4*)(pp + kb + 4 * j);
        }
    };
    auto stageB = [&](int buf, int kb) {
#pragma unroll
        for (int j = 0; j < 2; j++) {
            const int r = wave * 32 + j * 16;
            gl16(Bb + (size_t)(r + sr) * 256 + kb + sc, &Bsh[buf][r][0]);
        }
    };

    loadA(0);
    packA(0);
    stageB(0, 0);
    loadA(32);

    int i = 0;
    for (int kb = 0; kb < 256; kb += 32, ++i) {
        __syncthreads();
        if (kb + 32 < 256) {
            stageB((i + 1) & 1, kb + 32);
            packA((i + 1) & 1);
            if (kb + 64 < 256) loadA(kb + 64);
        }
        const int cf = i & 1;
        short8 af[4], bfr[4];
#pragma unroll
        for (int mt = 0; mt < 4; mt++)
            af[mt] = *(const short8*)&Ash[cf][wr * 64 + mt * 16 + lrow][quad * 8];
#pragma unroll
        for (int nt = 0; nt < 4; nt++)
            bfr[nt] = *(const short8*)&Bsh[cf][wc * 64 + nt * 16 + lrow][quad * 8];
#pragma unroll
        for (int mt = 0; mt < 4; mt++)
#pragma unroll
            for (int nt = 0; nt < 4; nt++)
                acc[mt][nt] = __builtin_amdgcn_mfma_f32_16x16x32_bf16(
                    af[mt], bfr[nt], acc[mt][nt], 0, 0, 0);
    }

    __syncthreads();
    auto bounce = (unsigned short (*)[136])smraw;
#pragma unroll
    for (int nt = 0; nt < 4; nt++) {
        const int cl = wc * 64 + nt * 16 + lrow;
        const float bv = bias[col0 + cl];
#pragma unroll
        for (int mt = 0; mt < 4; mt++) {
            f32x4 a = acc[mt][nt];
#pragma unroll
            for (int r = 0; r < 4; r++)
                bounce[wr * 64 + mt * 16 + quad * 4 + r][cl] = f2bf(a[r] + bv);
        }
    }
    __syncthreads();
    unsigned short* Cp; int ldc, c0;
    if (col0 < 256) { Cp = val;    ldc = 256; c0 = col0; }
    else            { Cp = qout16; ldc = 384; c0 = col0 - 256; }
#pragma unroll
    for (int pass = 0; pass < 8; pass++) {
        const int rl = pass * 16 + (t >> 4), ch = t & 15;
        *(uint4*)&Cp[(size_t)(row0 + rl) * ldc + c0 + ch * 8] =
            *(const uint4*)&bounce[rl][ch * 8];
    }
}

// ---------------------------------------------------------------------------
// Sampler: 4 queries per block. Phase 1: idx/weights for 4x128 (h,p) slots.
// Phase 2: 64 lanes per query, 16B (8-channel) gathers — 32 loads/thread,
// half the VMEM instructions of the 8B layout; p-halves combined via
// __shfl_xor(4). FFN weight-transpose blocks ride in the same launch.
// ---------------------------------------------------------------------------
__global__ void sampler(const unsigned short* __restrict__ val,
                        const unsigned short* __restrict__ qout16,
                        unsigned short* __restrict__ out,
                        const float* __restrict__ w_out, const float* __restrict__ w1,
                        const float* __restrict__ w2,
                        unsigned short* __restrict__ woT, unsigned short* __restrict__ w1T,
                        unsigned short* __restrict__ w2T) {
    __shared__ __align__(16) int   sIdx[4][128][4];
    __shared__ __align__(16) float sW[4][128][4];
    __shared__ float tileT[32][33];
    const int t = threadIdx.x;

    if (blockIdx.x >= MROWS / 4) {
        // weight transpose: 64 (w_out) + 512 (w1) + 512 (w2) blocks
        const int bk = (int)blockIdx.x - MROWS / 4;
        const float* W; unsigned short* WT; int K, N, tid;
        if (bk < 64)       { W = w_out; WT = woT;  K = 256;  N = 256;  tid = bk; }
        else if (bk < 576) { W = w1;    WT = w1T;  K = 256;  N = 2048; tid = bk - 64; }
        else               { W = w2;    WT = w2T;  K = 2048; N = 256;  tid = bk - 576; }
        const int ntx = N >> 5;
        const int nb = (tid % ntx) * 32, kb = (tid / ntx) * 32;
        const int tx = t & 31, ty = t >> 5;
#pragma unroll
        for (int i = 0; i < 32; i += 8)
            tileT[ty + i][tx] = W[(size_t)(kb + ty + i) * N + nb + tx];
        __syncthreads();
#pragma unroll
        for (int i = 0; i < 32; i += 8)
            WT[(size_t)(nb + ty + i) * K + kb + tx] = f2bf(tileT[tx][ty + i]);
        return;
    }

    const int pair = t & 127;            // (h,p) slot
    const int qsel = t >> 7;
    const int h1 = pair >> 4, p1 = pair & 15;
    const int lvl = p1 >> 2;

#pragma unroll
    for (int j = 0; j < 2; j++) {
        const int ql = qsel + 2 * j;
        const int bq = (int)blockIdx.x * 4 + ql;
        const int b = bq / LEN, q = bq % LEN;

        float refx, refy;
        if (q < 4096) {
            int rq = q >> 6, cq = q & 63;
            refx = (cq + 0.5f) * (1.0f / 64.0f);
            refy = (rq + 0.5f) * (1.0f / 64.0f);
        } else if (q < 5120) {
            int qq = q - 4096;
            int rq = qq >> 5, cq = qq & 31;
            refx = (cq + 0.5f) * (1.0f / 32.0f);
            refy = (rq + 0.5f) * (1.0f / 32.0f);
        } else if (q < 5376) {
            int qq = q - 5120;
            int rq = qq >> 4, cq = qq & 15;
            refx = (cq + 0.5f) * (1.0f / 16.0f);
            refy = (rq + 0.5f) * (1.0f / 16.0f);
        } else {
            int qq = q - 5376;
            int rq = qq >> 3, cq = qq & 7;
            refx = (cq + 0.5f) * (1.0f / 8.0f);
            refy = (rq + 0.5f) * (1.0f / 8.0f);
        }

        float lv = bf2f(qout16[(size_t)bq * 384 + 256 + pair]);
        float mx = lv;
#pragma unroll
        for (int o = 1; o < 16; o <<= 1) mx = fmaxf(mx, __shfl_xor(mx, o, 16));
        float e = expf(lv - mx);
        float s = e;
#pragma unroll
        for (int o = 1; o < 16; o <<= 1) s += __shfl_xor(s, o, 16);
        const float aw = e / s;

        const uint32 opair = *(const uint32*)&qout16[(size_t)bq * 384 + h1 * 32 + p1 * 2];
        const float ox = bf2f((unsigned short)opair);
        const float oy = bf2f((unsigned short)(opair >> 16));

        const int LST[4] = {0, 4096, 5120, 5376};
        const int WW = 64 >> lvl;
        const float rw = 1.0f / (float)WW;

        float x = (refx + ox * rw) * (float)WW - 0.5f;
        float y = (refy + oy * rw) * (float)WW - 0.5f;
        float x0f = floorf(x), y0f = floorf(y);
        float dx = x - x0f, dy = y - y0f;
        int x0 = (int)x0f, y0 = (int)y0f;

        const int base = (b * LEN + LST[lvl]) * 256 + h1 * 32;
        int xs[2] = {x0, x0 + 1}, ys[2] = {y0, y0 + 1};
        float wx[2] = {1.f - dx, dx}, wy[2] = {1.f - dy, dy};
        int ic[4]; float wc4[4];
#pragma unroll
        for (int cy = 0; cy < 2; cy++)
#pragma unroll
            for (int cx = 0; cx < 2; cx++) {
                int xi = xs[cx], yi = ys[cy];
                bool vld = (xi >= 0) && (xi < WW) && (yi >= 0) && (yi < WW);
                int xc = min(max(xi, 0), WW - 1);
                int yc = min(max(yi, 0), WW - 1);
                ic[cy * 2 + cx] = base + (yc * WW + xc) * 256;
                wc4[cy * 2 + cx] = vld ? wx[cx] * wy[cy] * aw : 0.f;
            }
        *(int4*)&sIdx[ql][pair][0] = make_int4(ic[0], ic[1], ic[2], ic[3]);
        *(float4*)&sW[ql][pair][0] = make_float4(wc4[0], wc4[1], wc4[2], wc4[3]);
    }
    __syncthreads();

    // phase 2: per query 64 lanes: 8 heads x 4 ch-groups(8ch) x 2 p-halves
    const int g = t >> 6;                  // query within block
    const int l6 = t & 63;
    const int h = l6 >> 3;
    const int chg = l6 & 3;                // 8-channel group
    const int ph = (l6 >> 2) & 1;          // p-half
    const int bq = (int)blockIdx.x * 4 + g;
    const unsigned short* vald = val + chg * 8;
    float a[8];
#pragma unroll
    for (int c = 0; c < 8; c++) a[c] = 0.f;
#pragma unroll
    for (int pi = 0; pi < 8; pi++) {
        const int r = h * 16 + ph * 8 + pi;
        int4 iv = *(const int4*)&sIdx[g][r][0];
        float4 wv = *(const float4*)&sW[g][r][0];
        uint4 u0 = *(const uint4*)(vald + iv.x);
        uint4 u1 = *(const uint4*)(vald + iv.y);
        uint4 u2 = *(const uint4*)(vald + iv.z);
        uint4 u3 = *(const uint4*)(vald + iv.w);
        acc8(a, u0, wv.x); acc8(a, u1, wv.y); acc8(a, u2, wv.z); acc8(a, u3, wv.w);
    }
#pragma unroll
    for (int c = 0; c < 8; c++) a[c] += __shfl_xor(a[c], 4, 64);
    if (ph == 0) {
        uint4 o;
        o.x = pack2(a[0], a[1]); o.y = pack2(a[2], a[3]);
        o.z = pack2(a[4], a[5]); o.w = pack2(a[6], a[7]);
        *(uint4*)&out[(size_t)bq * D + h * HD + chg * 8] = o;
    }
}

// ---------------------------------------------------------------------------
// Final LN, wave-per-row: out = LN(sum_z part16[z] + bias + rsd16) * g + be.
// ---------------------------------------------------------------------------
__global__ void add_ln4(const unsigned short* __restrict__ part16,
                        const float* __restrict__ bias,
                        const unsigned short* __restrict__ rsd16,
                        const float* __restrict__ g, const float* __restrict__ be,
                        float* __restrict__ out) {
    const int wave = threadIdx.x >> 6, lane = threadIdx.x & 63;
    const int row = blockIdx.x * 4 + wave;
    const int c0 = lane * 4;
    const size_t i = (size_t)row * 256 + c0;

    float v[4];
    {
        ushort4 r = *(const ushort4*)&rsd16[i];
        float4 bv = *(const float4*)&bias[c0];
        v[0] = bf2f(r.x) + bv.x; v[1] = bf2f(r.y) + bv.y;
        v[2] = bf2f(r.z) + bv.z; v[3] = bf2f(r.w) + bv.w;
    }
#pragma unroll
    for (int z = 0; z < 4; z++) {
        ushort4 p = *(const ushort4*)&part16[(size_t)z * MROWS * 256 + i];
        v[0] += bf2f(p.x); v[1] += bf2f(p.y); v[2] += bf2f(p.z); v[3] += bf2f(p.w);
    }
    float s1 = v[0] + v[1] + v[2] + v[3];
    float s2 = v[0] * v[0] + v[1] * v[1] + v[2] * v[2] + v[3] * v[3];
#pragma unroll
    for (int o = 32; o > 0; o >>= 1) {
        s1 += __shfl_xor(s1, o, 64);
        s2 += __shfl_xor(s2, o, 64);
    }
    const float mean = s1 * (1.0f / 256.0f);
    const float var = fmaxf(s2 * (1.0f / 256.0f) - mean * mean, 0.f);
    const float rstd = rsqrtf(var + 1e-5f);

    float4 gv = *(const float4*)&g[c0];
    float4 bev = *(const float4*)&be[c0];
    float4 o4;
    o4.x = (v[0] - mean) * rstd * gv.x + bev.x;
    o4.y = (v[1] - mean) * rstd * gv.y + bev.y;
    o4.z = (v[2] - mean) * rstd * gv.z + bev.z;
    o4.w = (v[3] - mean) * rstd * gv.w + bev.w;
    *(float4*)&out[i] = o4;
}

// ---------------------------------------------------------------------------
extern "C" void kernel_launch(void* const* d_in, const int* in_sizes, int n_in,
                              void* d_out, int out_size, void* d_ws, size_t ws_size,
                              hipStream_t stream) {
    const float* src     = (const float*)d_in[0];
    const float* pos     = (const float*)d_in[1];
    const float* w_value = (const float*)d_in[4];
    const float* b_value = (const float*)d_in[5];
    const float* w_off   = (const float*)d_in[6];
    const float* b_off   = (const float*)d_in[7];
    const float* w_attn  = (const float*)d_in[8];
    const float* b_attn  = (const float*)d_in[9];
    const float* w_out   = (const float*)d_in[10];
    const float* b_out   = (const float*)d_in[11];
    const float* w1      = (const float*)d_in[12];
    const float* b1      = (const float*)d_in[13];
    const float* w2      = (const float*)d_in[14];
    const float* b2      = (const float*)d_in[15];
    const float* g1      = (const float*)d_in[16];
    const float* be1     = (const float*)d_in[17];
    const float* g2      = (const float*)d_in[18];
    const float* be2     = (const float*)d_in[19];
    float* out = (float*)d_out;

    // ---- workspace layout ----
    size_t off = 0;
    auto alloc = [&](size_t bytes) -> char* {
        char* p = (char*)d_ws + off;
        off += (bytes + 255) & ~(size_t)255;
        return p;
    };
    unsigned short* wqvT = (unsigned short*)alloc((size_t)640 * 256 * 2);
    unsigned short* woT  = (unsigned short*)alloc(256 * 256 * 2);
    unsigned short* w1T  = (unsigned short*)alloc((size_t)2048 * 256 * 2);
    unsigned short* w2T  = (unsigned short*)alloc((size_t)256 * 2048 * 2);
    float* bqv           = (float*)alloc(640 * 4);

    unsigned short* qout = (unsigned short*)alloc((size_t)MROWS * 384 * 2);
    unsigned short* val  = (unsigned short*)alloc((size_t)MROWS * 256 * 2);
    unsigned short* attn = (unsigned short*)alloc((size_t)MROWS * 256 * 2);
    unsigned short* hb   = (unsigned short*)alloc((size_t)MROWS * 2048 * 2);
    unsigned short* xb16 = (unsigned short*)alloc((size_t)MROWS * 256 * 2);
    unsigned short* part = (unsigned short*)alloc((size_t)4 * MROWS * 256 * 2);

    // ---- small prep (wqv transposes + bias) ----
    prep_a<<<161, 256, 0, stream>>>(w_value, w_off, w_attn, b_value, b_off, b_attn,
                                    wqvT, bqv);

    // ---- attention ----
    qv_gemm<<<425, 256, 0, stream>>>(src, pos, wqvT, bqv, val, qout);
    // sampler (4 queries/block, 16B gathers) + appended FFN weight transposes
    sampler<<<MROWS / 4 + 1088, 256, 0, stream>>>(val, qout, attn,
                                                  w_out, w1, w2, woT, w1T, w2T);
    // x = LN(attn @ w_out + b_out + src) -> xb16   (fused, K=256)
    gemm_ln<<<340, 256, 0, stream>>>(attn, woT, b_out, src, g1, be1, xb16, 256);

    // ---- FFN ----
    ffn1_gemm<<<1360, 256, 0, stream>>>(xb16, w1T, b1, hb, 2048, 256, 256, 256);
    splitk_gemm<4><<<680, 256, 0, stream>>>(hb, w2T, part, 512, 2048, 2048);
    add_ln4<<<MROWS / 4, 256, 0, stream>>>(part, b2, xb16, g2, be2, out);
}